// Round 2
// baseline (429.180 us; speedup 1.0000x reference)
//
#include <hip/hip_runtime.h>
#include <hip/hip_bf16.h>

// BasicBlock sparse conv v9: model-independent slot cuts + masked-lane diagnostic.
// v8 counters: MfmaUtil 18 / VALU 15 / HBM 21% / Occ ~19 at 3 blocks/CU ->
// throughput ceiling, not latency. TA slot model: all-lanes 61M slots -> 99us
// (~= measured 95); active-only 31.6M -> 51us floor. Discriminate this round:
//  - conv1 = conv_kernel<1>: UNCONDITIONAL A-loads (sentinel -> zero row N_VOX)
//  - conv2 = conv_kernel<0>: branchy (exec-masked) A-loads
// If conv1 ~= conv2: masked lanes cost full -> compact-into-LDS next round.
// Also: sidx staged as int4 (-4M slots/conv), BN stats via shfl_xor butterfly
// (-8KB LDS, -1 barrier). LDS 52224 -> 44032.

#define N_VOX 200000
#define NP 200192            // padded rows: 782 blocks * 256 rows
#define EPS_BN 1e-5f

typedef __attribute__((ext_vector_type(8))) short bf16x8;   // 8 bf16 = 4 VGPRs
typedef __attribute__((ext_vector_type(4))) float f32x4;

// ---------------- prep kernels ----------------

__global__ void fill_kernel(int* __restrict__ nbrT, float* __restrict__ sums) {
    int p = blockIdx.y;                                   // plane 0..26
    long i = ((long)blockIdx.x * 256 + threadIdx.x) * 4;  // element in plane
    if (i < NP) {
        int4 v;
        if (p == 13) {   // identity plane (center tap); pad rows -> zero row
            v.x = (i + 0 < N_VOX) ? (int)i + 0 : N_VOX;
            v.y = (i + 1 < N_VOX) ? (int)i + 1 : N_VOX;
            v.z = (i + 2 < N_VOX) ? (int)i + 2 : N_VOX;
            v.w = (i + 3 < N_VOX) ? (int)i + 3 : N_VOX;
        } else {
            v.x = v.y = v.z = v.w = N_VOX;                // sentinel
        }
        *(int4*)(nbrT + (long)p * NP + i) = v;
    }
    if (p == 0 && blockIdx.x == 0 && threadIdx.x < 64) {  // zero sums[256]
        float4 z = {0.f, 0.f, 0.f, 0.f};
        ((float4*)sums)[threadIdx.x] = z;
    }
}

__global__ void scatter_kernel(const int* __restrict__ out_maps,
                               const int* __restrict__ in_maps,
                               int* __restrict__ nbrT) {
    int idx = blockIdx.x * 256 + threadIdx.x;       // < 26*65536
    int o = out_maps[idx];
    if (o < N_VOX) {
        int k = idx >> 16;                          // offset index 0..25
        int p = k + (k >= 13);                      // weight plane (skip center)
        nbrT[(long)p * NP + o] = in_maps[idx];
    }
}

__global__ void cast_x_kernel(const float* __restrict__ x,
                              __hip_bfloat16* __restrict__ xb) {
    long i = ((long)blockIdx.x * 256 + threadIdx.x) * 4;
    if (i >= (long)(N_VOX + 1) * 64) return;
    __hip_bfloat16 t[4];
    if (i < (long)N_VOX * 64) {
        float4 v = *(const float4*)(x + i);
        t[0] = __float2bfloat16(v.x); t[1] = __float2bfloat16(v.y);
        t[2] = __float2bfloat16(v.z); t[3] = __float2bfloat16(v.w);
    } else {
        t[0] = t[1] = t[2] = t[3] = __float2bfloat16(0.0f);  // zero row N
    }
    *(ushort4*)(xb + i) = *(ushort4*)t;
}

// W4: weights swizzled to MFMA B-fragment lane order.
// W4[((k*8 + g)*64 + lane)*8 + j],  g = ct*2+half, c = half*32+quad*8+j, d = ct*16+m.
__global__ void cast_w_kernel(const float* __restrict__ W1, const float* __restrict__ W2,
                              __hip_bfloat16* __restrict__ W1S, __hip_bfloat16* __restrict__ W2S) {
    int idx = blockIdx.x * 256 + threadIdx.x;
    if (idx >= 27 * 4096) return;
    int j    = idx & 7;
    int lane = (idx >> 3) & 63;
    int g    = idx >> 9;           // k*8 + ct*2 + half
    int half = g & 1, ct = (g >> 1) & 3, k = g >> 3;
    int m = lane & 15, quad = lane >> 4;
    int c = half * 32 + quad * 8 + j;
    int d = ct * 16 + m;
    int src = k * 4096 + c * 64 + d;
    W1S[idx] = __float2bfloat16(W1[src]);
    W2S[idx] = __float2bfloat16(W2[src]);
}

// ---------------- conv kernel ----------------
// block = 4 waves x 64 rows = 256 rows, cout 64.
// Iter k: lgkm-barrier | ds_write B(k+1) | vload B(k+2) | A-gather(k+1) | MFMA(k).
// DIAG=1: A-loads unconditional (sentinel -> zero row). DIAG=0: exec-masked.

template<int DIAG>
__global__ __launch_bounds__(256, 3) void conv_kernel(
    const __hip_bfloat16* __restrict__ xb,   // [(N+1)*64]
    const __hip_bfloat16* __restrict__ W4,   // [27*4096] swizzled
    const int* __restrict__ nbrT,            // [27*NP]
    __hip_bfloat16* __restrict__ h,          // [N*64] bf16
    float* __restrict__ sums)                // [128]: sum[64], sumsq[64]
{
    const int tid  = threadIdx.x;
    const int lane = tid & 63;
    const int wave = tid >> 6;
    const int m    = lane & 15;
    const int quad = lane >> 4;
    const int blockbase = blockIdx.x * 256;
    const int rbase = blockbase + wave * 64;           // 64 rows per wave

    __shared__ __align__(16) char smem[44032];
    int*            sidx = (int*)smem;                           // [27*256], 27648B
    __hip_bfloat16* bbuf = (__hip_bfloat16*)(smem + 27648);      // [2][4096],16384B
    __hip_bfloat16* trans = (__hip_bfloat16*)(smem + wave * 9216); // [64][72] post-loop (overlaps sidx/bbuf)

    // ---- stage neighbor indices (27 planes x 256 rows) as int4 ----
    for (int j = tid; j < 1728; j += 256) {
        int p = j >> 6, w = j & 63;
        ((int4*)sidx)[j] = *(const int4*)(nbrT + (long)p * NP + blockbase + w * 4);
    }

    // ---- stage B(0) into bbuf[0]: each wave 2 chunks of 1KB ----
    {
        const __hip_bfloat16* ws = W4 + wave * 1024 + lane * 8;
        bf16x8 b0 = *(const bf16x8*)(ws);
        bf16x8 b1 = *(const bf16x8*)(ws + 512);
        __hip_bfloat16* bd = bbuf + wave * 1024 + lane * 8;
        *(bf16x8*)bd = b0;
        *(bf16x8*)(bd + 512) = b1;
    }
    __syncthreads();   // sidx + bbuf[0] visible to all waves

    f32x4 acc[16];   // [tile*4 + ctile], 4 tiles x 4 ctiles
#pragma unroll
    for (int i = 0; i < 16; ++i) acc[i] = (f32x4){0.f, 0.f, 0.f, 0.f};

    const bf16x8 z8 = {0, 0, 0, 0, 0, 0, 0, 0};
    bf16x8 A[2][4][2];     // A ring depth 2: [stage][tile][half]
    bf16x8 btr0, btr1;     // B transit regs (next plane to ds_write)

#define LOAD_A(s, p)                                                        \
    {                                                                       \
        _Pragma("unroll")                                                   \
        for (int t = 0; t < 4; ++t) {                                       \
            int ii = sidx[(p) * 256 + wave * 64 + t * 16 + m];              \
            if (DIAG) {   /* unconditional: sentinel hits zero row N_VOX */ \
                const __hip_bfloat16* rr = xb + (long)ii * 64 + quad * 8;   \
                A[s][t][0] = *(const bf16x8*)rr;                            \
                A[s][t][1] = *(const bf16x8*)(rr + 32);                     \
            } else if (ii < N_VOX) {                                        \
                const __hip_bfloat16* rr = xb + (long)ii * 64 + quad * 8;   \
                A[s][t][0] = *(const bf16x8*)rr;                            \
                A[s][t][1] = *(const bf16x8*)(rr + 32);                     \
            } else { A[s][t][0] = z8; A[s][t][1] = z8; }                    \
        }                                                                   \
    }

#define LOAD_BT(p)                                                          \
    {                                                                       \
        const __hip_bfloat16* ws = W4 + (p) * 4096 + wave * 1024 + lane * 8;\
        btr0 = *(const bf16x8*)(ws);                                        \
        btr1 = *(const bf16x8*)(ws + 512);                                  \
    }

    // prologue: B(1) transit, A(0)
    LOAD_BT(1)
    LOAD_A(0, 0)

#pragma unroll
    for (int k = 0; k < 27; ++k) {
        // lgkm-only barrier: B dbuf writes/reads are ordered; A-gathers (vmem,
        // register-destined, wave-private) stay in flight across the barrier.
        asm volatile("s_waitcnt lgkmcnt(0)\n\ts_barrier" ::: "memory");
        if (k + 1 < 27) {  // ds_write B(k+1) -> bbuf[(k+1)&1]
            __hip_bfloat16* bd = bbuf + ((k + 1) & 1) * 4096 + wave * 1024 + lane * 8;
            *(bf16x8*)bd = btr0;
            *(bf16x8*)(bd + 512) = btr1;
        }
        if (k + 2 < 27) LOAD_BT(k + 2)
        if (k + 1 < 27) LOAD_A((k + 1) & 1, k + 1)
        __builtin_amdgcn_sched_barrier(0);
        // MFMA(k): B frags from bbuf[k&1] via ds_read_b128
        const __hip_bfloat16* bb = bbuf + (k & 1) * 4096;
        const int cs = k & 1;
#pragma unroll
        for (int ct = 0; ct < 4; ++ct) {
#pragma unroll
            for (int hf = 0; hf < 2; ++hf) {
                bf16x8 b = *(const bf16x8*)(bb + (ct * 2 + hf) * 512 + lane * 8);
#pragma unroll
                for (int t = 0; t < 4; ++t)
                    acc[t * 4 + ct] = __builtin_amdgcn_mfma_f32_16x16x32_bf16(A[cs][t][hf], b, acc[t * 4 + ct], 0, 0, 0);
            }
        }
        __builtin_amdgcn_sched_barrier(0);
    }
#undef LOAD_A
#undef LOAD_BT

    const bool valid = rbase < N_VOX;   // N_VOX % 64 == 0: per-wave granularity

    // ---- fused BN stats: shfl_xor butterfly over quads, per-wave atomics ----
    // acc[t*4+ct][r] = row t*16+quad*4+r, channel ct*16+m. Reduce over quads
    // (lanes m, m+16, m+32, m+48), then quad==0 lanes atomically accumulate.
    if (valid) {
#pragma unroll
        for (int ct = 0; ct < 4; ++ct) {
            float s = 0.f, q = 0.f;
#pragma unroll
            for (int t = 0; t < 4; ++t)
#pragma unroll
                for (int r = 0; r < 4; ++r) {
                    float v = acc[t * 4 + ct][r];
                    s += v; q += v * v;
                }
            s += __shfl_xor(s, 16); s += __shfl_xor(s, 32);
            q += __shfl_xor(q, 16); q += __shfl_xor(q, 32);
            if (quad == 0) {
                atomicAdd(&sums[ct * 16 + m], s);
                atomicAdd(&sums[64 + ct * 16 + m], q);
            }
        }
    }

    __syncthreads();   // all waves done with sidx/bbuf -> trans region reusable

    // ---- h store via wave-private LDS transpose (bf16, coalesced dwordx4) ----
    if (valid) {
#pragma unroll
        for (int t = 0; t < 4; ++t)
#pragma unroll
            for (int r = 0; r < 4; ++r)
#pragma unroll
                for (int ct = 0; ct < 4; ++ct)
                    trans[(t * 16 + quad * 4 + r) * 72 + ct * 16 + m] =
                        __float2bfloat16(acc[t * 4 + ct][r]);
#pragma unroll
        for (int i = 0; i < 8; ++i) {
            int row = i * 8 + (lane >> 3);
            bf16x8 v = *(const bf16x8*)(trans + row * 72 + (lane & 7) * 8);
            *(bf16x8*)(h + (long)(rbase + row) * 64 + (lane & 7) * 8) = v;
        }
    }
}

// ---------------- BN1 + relu + cast to bf16 (conv2 input) ----------------

__global__ void bnrelu_kernel(const __hip_bfloat16* __restrict__ h, const float* __restrict__ sums,
                              const float* __restrict__ gamma, const float* __restrict__ beta,
                              __hip_bfloat16* __restrict__ hb) {
    long i = ((long)blockIdx.x * 256 + threadIdx.x) * 4;
    if (i >= (long)(N_VOX + 1) * 64) return;
    __hip_bfloat16 t[4];
    if (i < (long)N_VOX * 64) {
        int c0 = (int)(i & 63);
        ushort4 raw = *(const ushort4*)(h + i);
        __hip_bfloat16 hv[4];
        *(ushort4*)hv = raw;
#pragma unroll
        for (int j = 0; j < 4; ++j) {
            int c = c0 + j;
            float mu  = sums[c] * (1.0f / N_VOX);
            float var = sums[64 + c] * (1.0f / N_VOX) - mu * mu;
            float rs  = rsqrtf(var + EPS_BN);
            float val = gamma[c] * (__bfloat162float(hv[j]) - mu) * rs + beta[c];
            t[j] = __float2bfloat16(fmaxf(val, 0.0f));
        }
    } else {
        t[0] = t[1] = t[2] = t[3] = __float2bfloat16(0.0f);   // zero row N
    }
    *(ushort4*)(hb + i) = *(ushort4*)t;
}

// ---------------- BN2 + residual + relu -> d_out ----------------

__global__ void final_kernel(const __hip_bfloat16* __restrict__ h, const float* __restrict__ x,
                             const float* __restrict__ sums, const float* __restrict__ gamma,
                             const float* __restrict__ beta, float* __restrict__ out) {
    long i = ((long)blockIdx.x * 256 + threadIdx.x) * 4;
    if (i >= (long)N_VOX * 64) return;
    int c0 = (int)(i & 63);
    ushort4 raw = *(const ushort4*)(h + i);
    __hip_bfloat16 hv[4];
    *(ushort4*)hv = raw;
    float4 xr = *(const float4*)(x + i);
    float xx[4] = {xr.x, xr.y, xr.z, xr.w};
    float oo[4];
#pragma unroll
    for (int j = 0; j < 4; ++j) {
        int c = c0 + j;
        float mu  = sums[c] * (1.0f / N_VOX);
        float var = sums[64 + c] * (1.0f / N_VOX) - mu * mu;
        float rs  = rsqrtf(var + EPS_BN);
        float val = gamma[c] * (__bfloat162float(hv[j]) - mu) * rs + beta[c] + xx[j];
        oo[j] = fmaxf(val, 0.0f);
    }
    float4 ov = {oo[0], oo[1], oo[2], oo[3]};
    *(float4*)(out + i) = ov;
}

// ---------------- launcher ----------------

extern "C" void kernel_launch(void* const* d_in, const int* in_sizes, int n_in,
                              void* d_out, int out_size, void* d_ws, size_t ws_size,
                              hipStream_t stream) {
    const float* x      = (const float*)d_in[0];
    const float* W1     = (const float*)d_in[1];
    const float* gamma1 = (const float*)d_in[2];
    const float* beta1  = (const float*)d_in[3];
    const float* W2     = (const float*)d_in[4];
    const float* gamma2 = (const float*)d_in[5];
    const float* beta2  = (const float*)d_in[6];
    const int* in_maps  = (const int*)d_in[7];
    const int* out_maps = (const int*)d_in[8];
    float* out = (float*)d_out;

    char* ws = (char*)d_ws;
    size_t off = 0;
    auto alloc = [&](size_t bytes) -> void* {
        void* p = ws + off;
        off = (off + bytes + 255) & ~(size_t)255;
        return p;
    };
    int* nbrT           = (int*)alloc((size_t)27 * NP * 4);                    // 21.6 MB
    __hip_bfloat16* xb  = (__hip_bfloat16*)alloc((size_t)(N_VOX + 1) * 64 * 2); // 25.6 MB (reused as h1b)
    __hip_bfloat16* W1S = (__hip_bfloat16*)alloc((size_t)27 * 4096 * 2);
    __hip_bfloat16* W2S = (__hip_bfloat16*)alloc((size_t)27 * 4096 * 2);
    __hip_bfloat16* h   = (__hip_bfloat16*)alloc((size_t)N_VOX * 64 * 2);      // 25.6 MB
    float* sums         = (float*)alloc(256 * 4);
    __hip_bfloat16* h1b = xb;   // xb dead after conv1; reuse for BN1(relu) output

    const long elem_x = (long)(N_VOX + 1) * 64;

    fill_kernel   <<<dim3((NP / 4 + 255) / 256, 27), 256, 0, stream>>>(nbrT, sums);
    scatter_kernel<<<26 * 65536 / 256, 256, 0, stream>>>(out_maps, in_maps, nbrT);
    cast_x_kernel <<<(int)((elem_x / 4 + 255) / 256), 256, 0, stream>>>(x, xb);
    cast_w_kernel <<<(27 * 4096 + 255) / 256, 256, 0, stream>>>(W1, W2, W1S, W2S);

    conv_kernel<1><<<NP / 256, 256, 0, stream>>>(xb, W1S, nbrT, h, sums);       // DIAG: unconditional loads
    bnrelu_kernel <<<(int)((elem_x / 4 + 255) / 256), 256, 0, stream>>>(h, sums, gamma1, beta1, h1b);

    conv_kernel<0><<<NP / 256, 256, 0, stream>>>(h1b, W2S, nbrT, h, sums + 128); // branchy baseline
    final_kernel  <<<(int)(((long)N_VOX * 64 / 4 + 255) / 256), 256, 0, stream>>>(h, x, sums + 128, gamma2, beta2, out);
}

// Round 3
// 325.548 us; speedup vs baseline: 1.3183x; 1.3183x over previous
//
#include <hip/hip_runtime.h>
#include <hip/hip_bf16.h>

// BasicBlock sparse conv v10: v9 post-mortem recovery + clean masked-lane A/B.
// v9 regressed both convs 95->147us. Suspect: shfl+per-wave-atomic BN stats
// (400K lane-atomics on 128 floats ~ 2 L2 lines, serialized tail) vs v8's
// LDS-reduce + 100K lane-atomics. v10: revert BN to v8 scheme (both convs),
// keep int4 sidx staging + lgkm-only barrier + depth-2 ring.
// A/B this round (conv1 vs conv2 are symmetric to +-0.4us, R1):
//   conv1 = conv_kernel<1>: UNCONDITIONAL A-loads (sentinel -> zero row)
//   conv2 = conv_kernel<0>: exec-masked A-loads (v8 behavior)
// Readout: conv1==conv2~95 -> masked lanes cost full TA price -> compaction.
//          conv1>>conv2    -> cost ~ active lanes -> attack instr overhead.
//          both ~147       -> int4 staging/co-compile is the culprit -> revert.

#define N_VOX 200000
#define NP 200192            // padded rows: 782 blocks * 256 rows
#define EPS_BN 1e-5f

typedef __attribute__((ext_vector_type(8))) short bf16x8;   // 8 bf16 = 4 VGPRs
typedef __attribute__((ext_vector_type(4))) float f32x4;

// ---------------- prep kernels ----------------

__global__ void fill_kernel(int* __restrict__ nbrT, float* __restrict__ sums) {
    int p = blockIdx.y;                                   // plane 0..26
    long i = ((long)blockIdx.x * 256 + threadIdx.x) * 4;  // element in plane
    if (i < NP) {
        int4 v;
        if (p == 13) {   // identity plane (center tap); pad rows -> zero row
            v.x = (i + 0 < N_VOX) ? (int)i + 0 : N_VOX;
            v.y = (i + 1 < N_VOX) ? (int)i + 1 : N_VOX;
            v.z = (i + 2 < N_VOX) ? (int)i + 2 : N_VOX;
            v.w = (i + 3 < N_VOX) ? (int)i + 3 : N_VOX;
        } else {
            v.x = v.y = v.z = v.w = N_VOX;                // sentinel
        }
        *(int4*)(nbrT + (long)p * NP + i) = v;
    }
    if (p == 0 && blockIdx.x == 0 && threadIdx.x < 64) {  // zero sums[256]
        float4 z = {0.f, 0.f, 0.f, 0.f};
        ((float4*)sums)[threadIdx.x] = z;
    }
}

__global__ void scatter_kernel(const int* __restrict__ out_maps,
                               const int* __restrict__ in_maps,
                               int* __restrict__ nbrT) {
    int idx = blockIdx.x * 256 + threadIdx.x;       // < 26*65536
    int o = out_maps[idx];
    if (o < N_VOX) {
        int k = idx >> 16;                          // offset index 0..25
        int p = k + (k >= 13);                      // weight plane (skip center)
        nbrT[(long)p * NP + o] = in_maps[idx];
    }
}

__global__ void cast_x_kernel(const float* __restrict__ x,
                              __hip_bfloat16* __restrict__ xb) {
    long i = ((long)blockIdx.x * 256 + threadIdx.x) * 4;
    if (i >= (long)(N_VOX + 1) * 64) return;
    __hip_bfloat16 t[4];
    if (i < (long)N_VOX * 64) {
        float4 v = *(const float4*)(x + i);
        t[0] = __float2bfloat16(v.x); t[1] = __float2bfloat16(v.y);
        t[2] = __float2bfloat16(v.z); t[3] = __float2bfloat16(v.w);
    } else {
        t[0] = t[1] = t[2] = t[3] = __float2bfloat16(0.0f);  // zero row N
    }
    *(ushort4*)(xb + i) = *(ushort4*)t;
}

// W4: weights swizzled to MFMA B-fragment lane order.
// W4[((k*8 + g)*64 + lane)*8 + j],  g = ct*2+half, c = half*32+quad*8+j, d = ct*16+m.
__global__ void cast_w_kernel(const float* __restrict__ W1, const float* __restrict__ W2,
                              __hip_bfloat16* __restrict__ W1S, __hip_bfloat16* __restrict__ W2S) {
    int idx = blockIdx.x * 256 + threadIdx.x;
    if (idx >= 27 * 4096) return;
    int j    = idx & 7;
    int lane = (idx >> 3) & 63;
    int g    = idx >> 9;           // k*8 + ct*2 + half
    int half = g & 1, ct = (g >> 1) & 3, k = g >> 3;
    int m = lane & 15, quad = lane >> 4;
    int c = half * 32 + quad * 8 + j;
    int d = ct * 16 + m;
    int src = k * 4096 + c * 64 + d;
    W1S[idx] = __float2bfloat16(W1[src]);
    W2S[idx] = __float2bfloat16(W2[src]);
}

// ---------------- conv kernel ----------------
// block = 4 waves x 64 rows = 256 rows, cout 64.
// Iter k: lgkm-barrier | ds_write B(k+1) | vload B(k+2) | A-gather(k+1) | MFMA(k).
// DIAG=1: A-loads unconditional (sentinel -> zero row). DIAG=0: exec-masked.

template<int DIAG>
__global__ __launch_bounds__(256, 3) void conv_kernel(
    const __hip_bfloat16* __restrict__ xb,   // [(N+1)*64]
    const __hip_bfloat16* __restrict__ W4,   // [27*4096] swizzled
    const int* __restrict__ nbrT,            // [27*NP]
    __hip_bfloat16* __restrict__ h,          // [N*64] bf16
    float* __restrict__ sums)                // [128]: sum[64], sumsq[64]
{
    const int tid  = threadIdx.x;
    const int lane = tid & 63;
    const int wave = tid >> 6;
    const int m    = lane & 15;
    const int quad = lane >> 4;
    const int blockbase = blockIdx.x * 256;
    const int rbase = blockbase + wave * 64;           // 64 rows per wave

    __shared__ __align__(16) char smem[52224];
    int*            sidx = (int*)smem;                           // [27*256], 27648B
    __hip_bfloat16* bbuf = (__hip_bfloat16*)(smem + 27648);      // [2][4096],16384B
    float*          lsum = (float*)(smem + 44032);               // [16][64], 4096B
    float*          lsq  = (float*)(smem + 48128);               // [16][64], 4096B
    __hip_bfloat16* trans = (__hip_bfloat16*)(smem + wave * 9216); // [64][72] post-loop (overlaps sidx/bbuf)

    // ---- stage neighbor indices (27 planes x 256 rows) as int4 ----
    for (int j = tid; j < 1728; j += 256) {
        int p = j >> 6, w = j & 63;
        ((int4*)sidx)[j] = *(const int4*)(nbrT + (long)p * NP + blockbase + w * 4);
    }

    // ---- stage B(0) into bbuf[0]: each wave 2 chunks of 1KB ----
    {
        const __hip_bfloat16* ws = W4 + wave * 1024 + lane * 8;
        bf16x8 b0 = *(const bf16x8*)(ws);
        bf16x8 b1 = *(const bf16x8*)(ws + 512);
        __hip_bfloat16* bd = bbuf + wave * 1024 + lane * 8;
        *(bf16x8*)bd = b0;
        *(bf16x8*)(bd + 512) = b1;
    }
    __syncthreads();   // sidx + bbuf[0] visible to all waves

    f32x4 acc[16];   // [tile*4 + ctile], 4 tiles x 4 ctiles
#pragma unroll
    for (int i = 0; i < 16; ++i) acc[i] = (f32x4){0.f, 0.f, 0.f, 0.f};

    const bf16x8 z8 = {0, 0, 0, 0, 0, 0, 0, 0};
    bf16x8 A[2][4][2];     // A ring depth 2: [stage][tile][half]
    bf16x8 btr0, btr1;     // B transit regs (next plane to ds_write)

#define LOAD_A(s, p)                                                        \
    {                                                                       \
        _Pragma("unroll")                                                   \
        for (int t = 0; t < 4; ++t) {                                       \
            int ii = sidx[(p) * 256 + wave * 64 + t * 16 + m];              \
            if (DIAG) {   /* unconditional: sentinel hits zero row N_VOX */ \
                const __hip_bfloat16* rr = xb + (long)ii * 64 + quad * 8;   \
                A[s][t][0] = *(const bf16x8*)rr;                            \
                A[s][t][1] = *(const bf16x8*)(rr + 32);                     \
            } else if (ii < N_VOX) {                                        \
                const __hip_bfloat16* rr = xb + (long)ii * 64 + quad * 8;   \
                A[s][t][0] = *(const bf16x8*)rr;                            \
                A[s][t][1] = *(const bf16x8*)(rr + 32);                     \
            } else { A[s][t][0] = z8; A[s][t][1] = z8; }                    \
        }                                                                   \
    }

#define LOAD_BT(p)                                                          \
    {                                                                       \
        const __hip_bfloat16* ws = W4 + (p) * 4096 + wave * 1024 + lane * 8;\
        btr0 = *(const bf16x8*)(ws);                                        \
        btr1 = *(const bf16x8*)(ws + 512);                                  \
    }

    // prologue: B(1) transit, A(0)
    LOAD_BT(1)
    LOAD_A(0, 0)

#pragma unroll
    for (int k = 0; k < 27; ++k) {
        // lgkm-only barrier: B dbuf writes/reads are ordered; A-gathers (vmem,
        // register-destined, wave-private) stay in flight across the barrier.
        asm volatile("s_waitcnt lgkmcnt(0)\n\ts_barrier" ::: "memory");
        if (k + 1 < 27) {  // ds_write B(k+1) -> bbuf[(k+1)&1]
            __hip_bfloat16* bd = bbuf + ((k + 1) & 1) * 4096 + wave * 1024 + lane * 8;
            *(bf16x8*)bd = btr0;
            *(bf16x8*)(bd + 512) = btr1;
        }
        if (k + 2 < 27) LOAD_BT(k + 2)
        if (k + 1 < 27) LOAD_A((k + 1) & 1, k + 1)
        __builtin_amdgcn_sched_barrier(0);
        // MFMA(k): B frags from bbuf[k&1] via ds_read_b128
        const __hip_bfloat16* bb = bbuf + (k & 1) * 4096;
        const int cs = k & 1;
#pragma unroll
        for (int ct = 0; ct < 4; ++ct) {
#pragma unroll
            for (int hf = 0; hf < 2; ++hf) {
                bf16x8 b = *(const bf16x8*)(bb + (ct * 2 + hf) * 512 + lane * 8);
#pragma unroll
                for (int t = 0; t < 4; ++t)
                    acc[t * 4 + ct] = __builtin_amdgcn_mfma_f32_16x16x32_bf16(A[cs][t][hf], b, acc[t * 4 + ct], 0, 0, 0);
            }
        }
        __builtin_amdgcn_sched_barrier(0);
    }
#undef LOAD_A
#undef LOAD_BT

    __syncthreads();   // all waves done with sidx/bbuf -> trans region reusable

    const bool valid = rbase < N_VOX;   // N_VOX % 64 == 0: per-wave granularity

    // ---- fused BN stats (v8 scheme: LDS reduce, 2 atomics per block) ----
#pragma unroll
    for (int ct = 0; ct < 4; ++ct) {
        float s = 0.f, q = 0.f;
        if (valid) {
#pragma unroll
            for (int t = 0; t < 4; ++t)
#pragma unroll
                for (int r = 0; r < 4; ++r) {
                    float v = acc[t * 4 + ct][r];
                    s += v; q += v * v;
                }
        }
        lsum[(wave * 4 + quad) * 64 + ct * 16 + m] = s;
        lsq [(wave * 4 + quad) * 64 + ct * 16 + m] = q;
    }
    __syncthreads();
    if (tid < 64) {
        float S = 0.f, Q = 0.f;
#pragma unroll
        for (int j = 0; j < 16; ++j) { S += lsum[j * 64 + tid]; Q += lsq[j * 64 + tid]; }
        atomicAdd(&sums[tid], S);
        atomicAdd(&sums[64 + tid], Q);
    }

    // ---- h store via wave-private LDS transpose (bf16, coalesced dwordx4) ----
    if (valid) {
#pragma unroll
        for (int t = 0; t < 4; ++t)
#pragma unroll
            for (int r = 0; r < 4; ++r)
#pragma unroll
                for (int ct = 0; ct < 4; ++ct)
                    trans[(t * 16 + quad * 4 + r) * 72 + ct * 16 + m] =
                        __float2bfloat16(acc[t * 4 + ct][r]);
#pragma unroll
        for (int i = 0; i < 8; ++i) {
            int row = i * 8 + (lane >> 3);
            bf16x8 v = *(const bf16x8*)(trans + row * 72 + (lane & 7) * 8);
            *(bf16x8*)(h + (long)(rbase + row) * 64 + (lane & 7) * 8) = v;
        }
    }
}

// ---------------- BN1 + relu + cast to bf16 (conv2 input) ----------------

__global__ void bnrelu_kernel(const __hip_bfloat16* __restrict__ h, const float* __restrict__ sums,
                              const float* __restrict__ gamma, const float* __restrict__ beta,
                              __hip_bfloat16* __restrict__ hb) {
    long i = ((long)blockIdx.x * 256 + threadIdx.x) * 4;
    if (i >= (long)(N_VOX + 1) * 64) return;
    __hip_bfloat16 t[4];
    if (i < (long)N_VOX * 64) {
        int c0 = (int)(i & 63);
        ushort4 raw = *(const ushort4*)(h + i);
        __hip_bfloat16 hv[4];
        *(ushort4*)hv = raw;
#pragma unroll
        for (int j = 0; j < 4; ++j) {
            int c = c0 + j;
            float mu  = sums[c] * (1.0f / N_VOX);
            float var = sums[64 + c] * (1.0f / N_VOX) - mu * mu;
            float rs  = rsqrtf(var + EPS_BN);
            float val = gamma[c] * (__bfloat162float(hv[j]) - mu) * rs + beta[c];
            t[j] = __float2bfloat16(fmaxf(val, 0.0f));
        }
    } else {
        t[0] = t[1] = t[2] = t[3] = __float2bfloat16(0.0f);   // zero row N
    }
    *(ushort4*)(hb + i) = *(ushort4*)t;
}

// ---------------- BN2 + residual + relu -> d_out ----------------

__global__ void final_kernel(const __hip_bfloat16* __restrict__ h, const float* __restrict__ x,
                             const float* __restrict__ sums, const float* __restrict__ gamma,
                             const float* __restrict__ beta, float* __restrict__ out) {
    long i = ((long)blockIdx.x * 256 + threadIdx.x) * 4;
    if (i >= (long)N_VOX * 64) return;
    int c0 = (int)(i & 63);
    ushort4 raw = *(const ushort4*)(h + i);
    __hip_bfloat16 hv[4];
    *(ushort4*)hv = raw;
    float4 xr = *(const float4*)(x + i);
    float xx[4] = {xr.x, xr.y, xr.z, xr.w};
    float oo[4];
#pragma unroll
    for (int j = 0; j < 4; ++j) {
        int c = c0 + j;
        float mu  = sums[c] * (1.0f / N_VOX);
        float var = sums[64 + c] * (1.0f / N_VOX) - mu * mu;
        float rs  = rsqrtf(var + EPS_BN);
        float val = gamma[c] * (__bfloat162float(hv[j]) - mu) * rs + beta[c] + xx[j];
        oo[j] = fmaxf(val, 0.0f);
    }
    float4 ov = {oo[0], oo[1], oo[2], oo[3]};
    *(float4*)(out + i) = ov;
}

// ---------------- launcher ----------------

extern "C" void kernel_launch(void* const* d_in, const int* in_sizes, int n_in,
                              void* d_out, int out_size, void* d_ws, size_t ws_size,
                              hipStream_t stream) {
    const float* x      = (const float*)d_in[0];
    const float* W1     = (const float*)d_in[1];
    const float* gamma1 = (const float*)d_in[2];
    const float* beta1  = (const float*)d_in[3];
    const float* W2     = (const float*)d_in[4];
    const float* gamma2 = (const float*)d_in[5];
    const float* beta2  = (const float*)d_in[6];
    const int* in_maps  = (const int*)d_in[7];
    const int* out_maps = (const int*)d_in[8];
    float* out = (float*)d_out;

    char* ws = (char*)d_ws;
    size_t off = 0;
    auto alloc = [&](size_t bytes) -> void* {
        void* p = ws + off;
        off = (off + bytes + 255) & ~(size_t)255;
        return p;
    };
    int* nbrT           = (int*)alloc((size_t)27 * NP * 4);                    // 21.6 MB
    __hip_bfloat16* xb  = (__hip_bfloat16*)alloc((size_t)(N_VOX + 1) * 64 * 2); // 25.6 MB (reused as h1b)
    __hip_bfloat16* W1S = (__hip_bfloat16*)alloc((size_t)27 * 4096 * 2);
    __hip_bfloat16* W2S = (__hip_bfloat16*)alloc((size_t)27 * 4096 * 2);
    __hip_bfloat16* h   = (__hip_bfloat16*)alloc((size_t)N_VOX * 64 * 2);      // 25.6 MB
    float* sums         = (float*)alloc(256 * 4);
    __hip_bfloat16* h1b = xb;   // xb dead after conv1; reuse for BN1(relu) output

    const long elem_x = (long)(N_VOX + 1) * 64;

    fill_kernel   <<<dim3((NP / 4 + 255) / 256, 27), 256, 0, stream>>>(nbrT, sums);
    scatter_kernel<<<26 * 65536 / 256, 256, 0, stream>>>(out_maps, in_maps, nbrT);
    cast_x_kernel <<<(int)((elem_x / 4 + 255) / 256), 256, 0, stream>>>(x, xb);
    cast_w_kernel <<<(27 * 4096 + 255) / 256, 256, 0, stream>>>(W1, W2, W1S, W2S);

    conv_kernel<1><<<NP / 256, 256, 0, stream>>>(xb, W1S, nbrT, h, sums);        // A: unconditional loads
    bnrelu_kernel <<<(int)((elem_x / 4 + 255) / 256), 256, 0, stream>>>(h, sums, gamma1, beta1, h1b);

    conv_kernel<0><<<NP / 256, 256, 0, stream>>>(h1b, W2S, nbrT, h, sums + 128); // B: exec-masked loads
    final_kernel  <<<(int)(((long)N_VOX * 64 / 4 + 255) / 256), 256, 0, stream>>>(h, x, sums + 128, gamma2, beta2, out);
}